// Round 1
// 715.436 us; speedup vs baseline: 1.0018x; 1.0018x over previous
//
#include <hip/hip_runtime.h>

// Problem constants
constexpr int KDIM   = 20480;   // 128*160 subsampled pixels
constexpr int MAUD   = 384;     // B*3 audio rows
constexpr int MTOT   = 512;     // + 128 visual rows
constexpr int DENC   = 128;
constexpr int SPLIT  = 64;      // split-K factor
constexpr int KCHUNK = KDIM / SPLIT;  // 320
constexpr int BK     = 64;
constexpr int MTILE  = 64;
constexpr int LDA    = 72;      // 64 + 8 bf16 pad
constexpr int LDB    = 72;

typedef __bf16 bf16_t;
typedef __bf16 v8bf __attribute__((ext_vector_type(8)));
typedef float  v4f  __attribute__((ext_vector_type(4)));

static __device__ inline unsigned short f2bf(float x) {
    union { float f; unsigned u; } a; a.f = x;
    unsigned r = a.u + 0x7FFFu + ((a.u >> 16) & 1u);   // RNE
    return (unsigned short)(r >> 16);
}

static __device__ inline float tanh_fast(float x) {
    // tanh(x) = 1 - 2/(exp(2x)+1); exp overflow -> 1, underflow -> -1 (no NaN)
    float e = __expf(2.f * x);
    return 1.f - 2.f * __builtin_amdgcn_rcpf(e + 1.f);
}

// ---------------------------------------------------------------------------
// Stage 1: OUT[512,128] = X[512,20480] @ W^T, X gathered stride-4 from f1/f2,
// converted to bf16 on the fly. Split-K partials P[row][split][128] fp32.
// Rows 0..383: (b,c) from f1 with W1.  Rows 384..511: b from f2 with W2.
//
// Software-pipelined: reg-staged global loads for tile k+1 issued before the
// barrier of tile k; LDS double-buffered; ONE barrier per K-step. Gather
// addresses are fully independent (no serial j/i increment chain).
// ---------------------------------------------------------------------------
__global__ __launch_bounds__(256) void gemm_stage1(
    const float* __restrict__ f1, const float* __restrict__ f2,
    const float* __restrict__ W1, const float* __restrict__ W2,
    float* __restrict__ P)
{
    __shared__ bf16_t lA[2][MTILE * LDA];   // 2 * 64*72*2B = 18.4 KB
    __shared__ bf16_t lB[2][DENC * LDB];    // 2 * 128*72*2B = 36.9 KB

    const int bx    = blockIdx.x;
    const int mtile = bx >> 6;     // 0..7
    const int s     = bx & 63;     // split id 0..63
    const int t     = threadIdx.x;

    // A staging: thread -> (row, 16-wide k segment)
    const int arow = t >> 2;            // 0..63
    const int kseg = (t & 3) * 16;      // 0/16/32/48
    const int r    = mtile * MTILE + arow;
    const float* abase = (r < MAUD) ? (f1 + (size_t)r * 327680)
                                    : (f2 + (size_t)(r - MAUD) * 327680);
    // B staging: thread -> (n row, 32-wide k segment)
    const int bn  = t >> 1;             // 0..127
    const int bk0 = (t & 1) * 32;
    const float* wbase = ((mtile < 6) ? W1 : W2)
                       + (size_t)bn * KDIM + s * KCHUNK + bk0;

    // compute mapping: 4 waves in 2x2 grid, each wave 32x64 (2x4 mfma tiles)
    const int wave = t >> 6, lane = t & 63;
    const int wr  = wave >> 1, wc = wave & 1;
    const int l15 = lane & 15, lq = lane >> 4;

    v4f acc[2][4];
#pragma unroll
    for (int a = 0; a < 2; ++a)
#pragma unroll
        for (int b = 0; b < 4; ++b) acc[a][b] = (v4f)0.f;

    // register staging for the pipelined tile
    float  av[16];
    float4 bv[8];

    // subsampled element d -> source float index: i = d/160 (subsampled row),
    // src = i*2560 + (d-160i)*4 = 4*d + 1920*i. All 16 addresses independent:
    // i = i0 + (j0+e >= 160), at most one row wrap inside a 16-segment.
#define LOAD_TILE(bk_) do {                                                   \
    const int db_ = s * KCHUNK + kseg + (bk_) * BK;                           \
    const int i0_ = db_ / 160;                                                \
    const int j0_ = db_ - i0_ * 160;                                          \
    _Pragma("unroll")                                                         \
    for (int e = 0; e < 16; ++e) {                                            \
        const int i_ = i0_ + ((j0_ + e) >= 160);                              \
        av[e] = abase[4 * (db_ + e) + 1920 * i_];                             \
    }                                                                         \
    const float4* wp_ = (const float4*)(wbase + (bk_) * BK);                  \
    _Pragma("unroll")                                                         \
    for (int g = 0; g < 8; ++g) bv[g] = wp_[g];                               \
} while (0)

#define STORE_TILE(buf_) do {                                                 \
    unsigned pk_[8];                                                          \
    _Pragma("unroll")                                                         \
    for (int q = 0; q < 8; ++q)                                               \
        pk_[q] = (unsigned)f2bf(av[2 * q]) |                                  \
                 ((unsigned)f2bf(av[2 * q + 1]) << 16);                       \
    *(uint4*)&lA[buf_][arow * LDA + kseg] =                                   \
        make_uint4(pk_[0], pk_[1], pk_[2], pk_[3]);                           \
    *(uint4*)&lA[buf_][arow * LDA + kseg + 8] =                               \
        make_uint4(pk_[4], pk_[5], pk_[6], pk_[7]);                           \
    _Pragma("unroll")                                                         \
    for (int g = 0; g < 4; ++g) {                                             \
        const float4 x_ = bv[2 * g], y_ = bv[2 * g + 1];                      \
        uint4 w_;                                                             \
        w_.x = (unsigned)f2bf(x_.x) | ((unsigned)f2bf(x_.y) << 16);           \
        w_.y = (unsigned)f2bf(x_.z) | ((unsigned)f2bf(x_.w) << 16);           \
        w_.z = (unsigned)f2bf(y_.x) | ((unsigned)f2bf(y_.y) << 16);           \
        w_.w = (unsigned)f2bf(y_.z) | ((unsigned)f2bf(y_.w) << 16);           \
        *(uint4*)&lB[buf_][bn * LDB + bk0 + g * 8] = w_;                      \
    }                                                                         \
} while (0)

    // prologue: tile 0 into buf 0
    LOAD_TILE(0);
    STORE_TILE(0);

    int cur = 0;
#pragma unroll
    for (int bk = 0; bk < KCHUNK / BK; ++bk) {   // 5 iterations
        if (bk < KCHUNK / BK - 1) LOAD_TILE(bk + 1);   // issue early (regs)
        __syncthreads();                                // buf[cur] ready
        // ---- MFMA over BK=64 (two K=32 steps) from buf[cur]
#pragma unroll
        for (int kk = 0; kk < 2; ++kk) {
            const int kl = kk * 32 + lq * 8;
            v8bf fa[2], fb[4];
#pragma unroll
            for (int mi = 0; mi < 2; ++mi)
                fa[mi] = *(const v8bf*)&lA[cur][(wr * 32 + mi * 16 + l15) * LDA + kl];
#pragma unroll
            for (int ni = 0; ni < 4; ++ni)
                fb[ni] = *(const v8bf*)&lB[cur][(wc * 64 + ni * 16 + l15) * LDB + kl];
#pragma unroll
            for (int mi = 0; mi < 2; ++mi)
#pragma unroll
                for (int ni = 0; ni < 4; ++ni)
                    acc[mi][ni] = __builtin_amdgcn_mfma_f32_16x16x32_bf16(
                        fa[mi], fb[ni], acc[mi][ni], 0, 0, 0);
        }
        // convert+write NEXT tile into the other buffer (vmcnt drain hides
        // under the ds_read+MFMA above; safe: all waves read only buf[cur]
        // this iteration, and the top-of-loop barrier ordered the previous
        // readers of buf[cur^1]).
        if (bk < KCHUNK / BK - 1) { STORE_TILE(cur ^ 1); cur ^= 1; }
    }
#undef LOAD_TILE
#undef STORE_TILE

    // epilogue: C/D layout col=lane&15, row=(lane>>4)*4+reg
#pragma unroll
    for (int mi = 0; mi < 2; ++mi)
#pragma unroll
        for (int ni = 0; ni < 4; ++ni)
#pragma unroll
            for (int v = 0; v < 4; ++v) {
                int row = mtile * MTILE + wr * 32 + mi * 16 + lq * 4 + v;
                int col = wc * 64 + ni * 16 + l15;
                P[((size_t)row * SPLIT + s) * DENC + col] = acc[mi][ni][v];
            }
}

// ---------------------------------------------------------------------------
// Stage 2: per-batch fused attention tail. grid = 256: block = (batch, a/v).
// ---------------------------------------------------------------------------
__global__ __launch_bounds__(256) void stage2(
    const float* __restrict__ P,
    const float* __restrict__ b1, const float* __restrict__ b2,
    const float* __restrict__ Aa, const float* __restrict__ Av,
    const float* __restrict__ Wa, const float* __restrict__ Wv,
    const float* __restrict__ Wca, const float* __restrict__ Wcv,
    const float* __restrict__ Wha, const float* __restrict__ Whv,
    float* __restrict__ out)
{
    __shared__ float s_aud[3][128];
    __shared__ float s_vis[128];
    __shared__ float s_M[3][256];      // audio: Aav rows; visual: row0 = sum_i Vav[i][m]
    __shared__ float s_Wc[32 * 256];
    __shared__ float s_H[2][128][33];  // +1 pad: bank-conflict-free

    const int gid = blockIdx.x;
    const int b   = gid >> 1;
    const int isv = gid & 1;
    const int t   = threadIdx.x;

    // phase 0: reduce split-K partials (+bias) into LDS
    for (int o = t; o < 512; o += 256) {
        if (o < 384) {
            const int c = o >> 7, k = o & 127;
            float acc = b1[k];
            const float* p = P + (size_t)(3 * b + c) * SPLIT * 128 + k;
#pragma unroll 4
            for (int sp = 0; sp < SPLIT; ++sp) acc += p[sp * 128];
            s_aud[c][k] = acc;
        } else {
            const int k = o - 384;
            float acc = b2[k];
            const float* p = P + (size_t)(384 + b) * SPLIT * 128 + k;
#pragma unroll 4
            for (int sp = 0; sp < SPLIT; ++sp) acc += p[sp * 128];
            s_vis[k] = acc;
        }
    }
    // stage Wca/Wcv
    {
        const float4* wg = (const float4*)(isv ? Wcv : Wca);
        float4* ws4 = (float4*)s_Wc;
        for (int idx = t; idx < 2048; idx += 256) ws4[idx] = wg[idx];
    }
    __syncthreads();

    // phase 1: s_M
    {
        const int m = t;  // exactly 256 threads
        const float av0 = (m < 128) ? s_aud[0][m] : s_vis[m - 128];
        const float av1 = (m < 128) ? s_aud[1][m] : s_vis[m - 128];
        const float av2 = (m < 128) ? s_aud[2][m] : s_vis[m - 128];
        if (!isv) {
#pragma unroll
            for (int i = 0; i < 3; ++i)
                s_M[i][m] = Aa[3 * i] * av0 + Aa[3 * i + 1] * av1 + Aa[3 * i + 2] * av2;
        } else {
            const float c0 = Av[0] + Av[3] + Av[6];
            const float c1 = Av[1] + Av[4] + Av[7];
            const float c2 = Av[2] + Av[5] + Av[8];
            s_M[0][m] = c0 * av0 + c1 * av1 + c2 * av2;
        }
    }
    __syncthreads();

    // phase 2: per-(k,half) online tanh-attention + H accumulation
    {
        const int k = t & 127, half = t >> 7;
        float hacc[32];
#pragma unroll
        for (int h = 0; h < 32; ++h) hacc[h] = 0.f;
        const float scale = 0.0625f;  // 1/sqrt(256)
        const float4* M4 = (const float4*)s_M;   // [3][64]
        const float4* W4 = (const float4*)s_Wc;  // [32][64]
        float a0 = 0.f, a1 = 0.f, a2 = 0.f, vk = 0.f;
        if (!isv) { a0 = s_aud[0][k]; a1 = s_aud[1][k]; a2 = s_aud[2][k]; }
        else      { vk = s_vis[k]; }
        for (int cc = 0; cc < 32; ++cc) {
            const int mi = half * 32 + cc;
            const float4 m0 = M4[mi];
            float s0, s1, s2, s3;
            if (!isv) {
                const float4 m1 = M4[64 + mi], m2 = M4[128 + mi];
                s0 = scale * (a0 * m0.x + a1 * m1.x + a2 * m2.x);
                s1 = scale * (a0 * m0.y + a1 * m1.y + a2 * m2.y);
                s2 = scale * (a0 * m0.z + a1 * m1.z + a2 * m2.z);
                s3 = scale * (a0 * m0.w + a1 * m1.w + a2 * m2.w);
            } else {
                s0 = scale * vk * m0.x; s1 = scale * vk * m0.y;
                s2 = scale * vk * m0.z; s3 = scale * vk * m0.w;
            }
            const float t0 = tanh_fast(s0), t1 = tanh_fast(s1);
            const float t2 = tanh_fast(s2), t3 = tanh_fast(s3);
#pragma unroll
            for (int h = 0; h < 32; ++h) {
                const float4 w = W4[h * 64 + mi];
                hacc[h] = fmaf(t0, w.x, fmaf(t1, w.y, fmaf(t2, w.z, fmaf(t3, w.w, hacc[h]))));
            }
        }
#pragma unroll
        for (int h = 0; h < 32; ++h) s_H[half][k][h] = hacc[h];
    }
    __syncthreads();

    // phase 3: relu(H + linear-bias), project with Wha/Whv, add residual, store
    if (t < 128) {
        const int k = t;
        const float* Wh  = isv ? Whv : Wha;   // (3,32)
        const float* Wab = isv ? Wv  : Wa;    // (32,3)
        float p0, p1, p2;
        if (!isv) { p0 = s_aud[0][k]; p1 = s_aud[1][k]; p2 = s_aud[2][k]; }
        else      { p0 = p1 = p2 = s_vis[k]; }
        float o0 = 0.f, o1 = 0.f, o2 = 0.f;
#pragma unroll
        for (int h = 0; h < 32; ++h) {
            float wb = p0 * Wab[h * 3] + p1 * Wab[h * 3 + 1] + p2 * Wab[h * 3 + 2];
            float hv = s_H[0][k][h] + s_H[1][k][h] + wb;
            hv = fmaxf(hv, 0.f);
            o0 = fmaf(hv, Wh[h], o0);
            o1 = fmaf(hv, Wh[32 + h], o1);
            o2 = fmaf(hv, Wh[64 + h], o2);
        }
        const size_t ob = (size_t)b * 768 + (isv ? 128 : 0) + k;
        if (!isv) {
            out[ob]       = o0 + s_aud[0][k];
            out[ob + 256] = o1 + s_aud[1][k];
            out[ob + 512] = o2 + s_aud[2][k];
        } else {
            const float v = s_vis[k];
            out[ob]       = o0 + v;
            out[ob + 256] = o1 + v;
            out[ob + 512] = o2 + v;
        }
    }
}

extern "C" void kernel_launch(void* const* d_in, const int* in_sizes, int n_in,
                              void* d_out, int out_size, void* d_ws, size_t ws_size,
                              hipStream_t stream) {
    const float* f1  = (const float*)d_in[0];
    const float* f2  = (const float*)d_in[1];
    const float* W1  = (const float*)d_in[2];
    const float* b1  = (const float*)d_in[3];
    const float* W2  = (const float*)d_in[4];
    const float* b2  = (const float*)d_in[5];
    const float* Aa  = (const float*)d_in[6];
    const float* Av  = (const float*)d_in[7];
    const float* Wa  = (const float*)d_in[8];
    const float* Wv  = (const float*)d_in[9];
    const float* Wca = (const float*)d_in[10];
    const float* Wcv = (const float*)d_in[11];
    const float* Wha = (const float*)d_in[12];
    const float* Whv = (const float*)d_in[13];
    float* P   = (float*)d_ws;   // 512 * 64 * 128 * 4 B = 16 MiB
    float* out = (float*)d_out;

    hipLaunchKernelGGL(gemm_stage1, dim3(512), dim3(256), 0, stream,
                       f1, f2, W1, W2, P);
    hipLaunchKernelGGL(stage2, dim3(256), dim3(256), 0, stream,
                       P, b1, b2, Aa, Av, Wa, Wv, Wca, Wcv, Wha, Whv, out);
}